// Round 14
// baseline (537.386 us; speedup 1.0000x reference)
//
#include <hip/hip_runtime.h>
#include <hip/hip_bf16.h>
#include <math.h>

#define N_NODES 50000
#define N_EDGES 1000000
#define D 64
#define ED 16
#define NEG 0.2f

__device__ __forceinline__ float wave_sum(float v) {
  #pragma unroll
  for (int m = 32; m >= 1; m >>= 1) v += __shfl_xor(v, m, 64);
  return v;
}

// ---- zero the histogram counters ----
__global__ void k_init(int* __restrict__ cursor) {
  int i = blockIdx.x * 256 + threadIdx.x;
  if (i < N_NODES) cursor[i] = 0;
}

// ---- x_l = x@Wl + bl (stored bf16 for cheap gathers); x_r = x@Wr + br (fp32) ----
__global__ __launch_bounds__(256) void k_transform(
    const float* __restrict__ x,
    const float* __restrict__ Wl, const float* __restrict__ bl,
    const float* __restrict__ Wr, const float* __restrict__ br,
    __hip_bfloat16* __restrict__ xlb, float* __restrict__ xr) {
  __shared__ float sW[2 * D * D];  // 32 KiB
  float* sWl = sW;
  float* sWr = sW + D * D;
  int t = threadIdx.x;
  for (int q = t; q < D * D / 4; q += 256) {
    ((float4*)sWl)[q] = ((const float4*)Wl)[q];
    ((float4*)sWr)[q] = ((const float4*)Wr)[q];
  }
  __syncthreads();
  int lane = t & 63;
  int row = blockIdx.x * 4 + (t >> 6);
  if (row >= N_NODES) return;
  float xv = x[row * D + lane];
  float accl = bl[lane], accr = br[lane];
  #pragma unroll
  for (int k = 0; k < D; k++) {
    float xk = __shfl(xv, k, 64);
    accl = fmaf(xk, sWl[k * D + lane], accl);
    accr = fmaf(xk, sWr[k * D + lane], accr);
  }
  xlb[row * D + lane] = __float2bfloat16(accl);
  xr[row * D + lane] = accr;
}

// ---- histogram of dst (validated) ----
__global__ void k_hist(const int* __restrict__ ei, int* __restrict__ cursor) {
  int e = blockIdx.x * 256 + threadIdx.x;
  if (e < N_EDGES) atomicAdd(&cursor[ei[N_EDGES + e]], 1);
}

// ---- 3-kernel exclusive scan of counts -> row_start (validated) ----
__global__ void k_scan_a(const int* __restrict__ counts, int* __restrict__ row_start,
                         int* __restrict__ bsum) {
  __shared__ int sb[256];
  int t = threadIdx.x;
  int i = blockIdx.x * 256 + t;
  int v = (i < N_NODES) ? counts[i] : 0;
  sb[t] = v;
  __syncthreads();
  for (int off = 1; off < 256; off <<= 1) {
    int add = (t >= off) ? sb[t - off] : 0;
    __syncthreads();
    sb[t] += add;
    __syncthreads();
  }
  if (i < N_NODES) row_start[i] = sb[t] - v;  // exclusive
  if (t == 255) bsum[blockIdx.x] = sb[t];
}
__global__ void k_scan_b(int* __restrict__ bsum, int nb) {
  __shared__ int sb[256];
  int t = threadIdx.x;
  int v = (t < nb) ? bsum[t] : 0;
  sb[t] = v;
  __syncthreads();
  for (int off = 1; off < 256; off <<= 1) {
    int add = (t >= off) ? sb[t - off] : 0;
    __syncthreads();
    sb[t] += add;
    __syncthreads();
  }
  if (t < nb) bsum[t] = sb[t] - v;  // exclusive
}
__global__ void k_scan_c(int* __restrict__ row_start, const int* __restrict__ bsum,
                         int* __restrict__ cursor) {
  int t = threadIdx.x;
  int i = blockIdx.x * 256 + t;
  if (i < N_NODES) {
    int r = row_start[i] + bsum[blockIdx.x];
    row_start[i] = r;
    cursor[i] = r;
  }
  if (i == 0) row_start[N_NODES] = N_EDGES;
}

// ---- counting-sort scatter: one packed {e, src} 8B write per edge ----
__global__ void k_scatter(const int* __restrict__ ei, int* __restrict__ cursor,
                          int2* __restrict__ perm) {
  int e = blockIdx.x * 256 + threadIdx.x;
  if (e >= N_EDGES) return;
  int s = ei[e];
  int d = ei[N_EDGES + e];
  int pos = atomicAdd(&cursor[d], 1);
  perm[pos] = make_int2(e, s);
}

// ---- fused per-node online-softmax attention + aggregation (wave per node) ----
// 2-stage software pipeline: while computing edge i, the row-gathers for i+1
// and the idx-load for i+2 are in flight. bf16 row kept as raw ushort until
// use so the conversion's waitcnt doesn't land at the issue site.
__global__ __launch_bounds__(256) void k_fused(
    const float* __restrict__ ea, const float* __restrict__ We,
    const float* __restrict__ att,
    const __hip_bfloat16* __restrict__ xlb, const float* __restrict__ xr,
    const int* __restrict__ row_start, const int2* __restrict__ perm,
    const float* __restrict__ bias, float* __restrict__ out) {
  __shared__ float sWe[ED * D];  // 4 KiB
  __shared__ float satt[D];
  int t = threadIdx.x;
  for (int q = t; q < ED * D / 4; q += 256) ((float4*)sWe)[q] = ((const float4*)We)[q];
  if (t < D) satt[t] = att[t];
  __syncthreads();
  int lane = t & 63;
  int n = blockIdx.x * 4 + (t >> 6);
  if (n >= N_NODES) return;
  int start = row_start[n];
  int end = row_start[n + 1];

  float xrv = xr[(size_t)n * D + lane];  // one linear row read per node
  float av = satt[lane];
  float m = -INFINITY, lsum = 0.f, O = 0.f;

  const unsigned short* xlr16 = (const unsigned short*)xlb;

  if (start < end) {
    // rows for edge `start`
    int2 p0 = perm[start];
    int e0 = __builtin_amdgcn_readfirstlane(p0.x);
    int s0 = __builtin_amdgcn_readfirstlane(p0.y);
    unsigned short xlr = xlr16[(size_t)s0 * D + lane];
    float eav = (lane < ED) ? ea[(size_t)e0 * ED + lane] : 0.f;
    // pending idx for edge start+1
    int i1 = (start + 1 < end) ? start + 1 : start;
    int2 pp = perm[i1];

    for (int i = start; i < end; ++i) {
      // form next-row addresses from pending idx; issue next-row gathers
      int e_n = __builtin_amdgcn_readfirstlane(pp.x);
      int s_n = __builtin_amdgcn_readfirstlane(pp.y);
      unsigned short xlr_n = xlr16[(size_t)s_n * D + lane];
      float eav_n = (lane < ED) ? ea[(size_t)e_n * ED + lane] : 0.f;
      // issue idx load for i+2 (clamped; wave-uniform)
      int i2 = (i + 2 < end) ? i + 2 : i1;
      pp = perm[i2];

      // compute edge i
      float xlv = __uint_as_float(((unsigned)xlr) << 16);  // bf16 -> f32
      float acc = 0.f;
      #pragma unroll
      for (int k = 0; k < ED; k++) {
        float ek = __shfl(eav, k, 64);
        acc = fmaf(ek, sWe[k * D + lane], acc);
      }
      float h = xlv + xrv + acc;
      h = (h > 0.f) ? h : NEG * h;
      float logit = wave_sum(h * av);
      // online softmax update
      float mn = fmaxf(m, logit);
      float sc = __expf(m - mn);
      float p = __expf(logit - mn);
      lsum = fmaf(lsum, sc, p);
      O = O * sc + p * xlv;
      m = mn;
      // rotate pipeline
      xlr = xlr_n;
      eav = eav_n;
    }
  }
  out[(size_t)n * D + lane] = O / (lsum + 1e-16f) + bias[lane];
}

static inline char* align_up(char* p, size_t a) {
  return (char*)(((uintptr_t)p + a - 1) & ~(uintptr_t)(a - 1));
}

extern "C" void kernel_launch(void* const* d_in, const int* in_sizes, int n_in,
                              void* d_out, int out_size, void* d_ws, size_t ws_size,
                              hipStream_t stream) {
  const float* x   = (const float*)d_in[0];
  const int* ei    = (const int*)d_in[1];   // harness passes integer inputs as int32 (validated)
  const float* ea  = (const float*)d_in[2];
  const float* Wl  = (const float*)d_in[3];
  const float* bl  = (const float*)d_in[4];
  const float* Wr  = (const float*)d_in[5];
  const float* br  = (const float*)d_in[6];
  const float* We  = (const float*)d_in[7];
  const float* att = (const float*)d_in[8];
  const float* bias = (const float*)d_in[9];
  float* out = (float*)d_out;

  // workspace carve-up (~28 MB), 256B-aligned blocks
  char* w = (char*)d_ws;
  __hip_bfloat16* xlb = (__hip_bfloat16*)w; w = align_up(w + (size_t)N_NODES * D * 2, 256);
  float* xr       = (float*)w; w = align_up(w + (size_t)N_NODES * D * 4, 256);
  int* row_start  = (int*)w;   w = align_up(w + (size_t)(N_NODES + 1) * 4, 256);
  int* cursor     = (int*)w;   w = align_up(w + (size_t)N_NODES * 4, 256);
  int* bsum       = (int*)w;   w = align_up(w + 256 * 4, 256);
  int2* perm      = (int2*)w;  w = align_up(w + (size_t)N_EDGES * 8, 256);

  const int NB = (N_NODES + 255) / 256;  // 196

  k_init<<<NB, 256, 0, stream>>>(cursor);
  k_transform<<<N_NODES / 4, 256, 0, stream>>>(x, Wl, bl, Wr, br, xlb, xr);
  k_hist<<<(N_EDGES + 255) / 256, 256, 0, stream>>>(ei, cursor);
  k_scan_a<<<NB, 256, 0, stream>>>(cursor, row_start, bsum);
  k_scan_b<<<1, 256, 0, stream>>>(bsum, NB);
  k_scan_c<<<NB, 256, 0, stream>>>(row_start, bsum, cursor);
  k_scatter<<<(N_EDGES + 255) / 256, 256, 0, stream>>>(ei, cursor, perm);
  k_fused<<<(N_NODES + 3) / 4, 256, 0, stream>>>(ea, We, att, xlb, xr, row_start,
                                                 perm, bias, out);
}

// Round 15
// 528.935 us; speedup vs baseline: 1.0160x; 1.0160x over previous
//
#include <hip/hip_runtime.h>
#include <hip/hip_bf16.h>
#include <math.h>

#define N_NODES 50000
#define N_EDGES 1000000
#define D 64
#define ED 16
#define NEG 0.2f

__device__ __forceinline__ float wave_sum(float v) {
  #pragma unroll
  for (int m = 32; m >= 1; m >>= 1) v += __shfl_xor(v, m, 64);
  return v;
}

__device__ __forceinline__ unsigned short f2bf(float x) {
  __hip_bfloat16 h = __float2bfloat16(x);
  return *(unsigned short*)&h;
}
__device__ __forceinline__ float bf2f(unsigned short u) {
  return __uint_as_float(((unsigned)u) << 16);
}

// ---- x_l = x@Wl + bl (stored bf16 for cheap gathers); x_r = x@Wr + br (fp32) ----
__global__ __launch_bounds__(256) void k_transform(
    const float* __restrict__ x,
    const float* __restrict__ Wl, const float* __restrict__ bl,
    const float* __restrict__ Wr, const float* __restrict__ br,
    __hip_bfloat16* __restrict__ xlb, float* __restrict__ xr) {
  __shared__ float sW[2 * D * D];  // 32 KiB
  float* sWl = sW;
  float* sWr = sW + D * D;
  int t = threadIdx.x;
  for (int q = t; q < D * D / 4; q += 256) {
    ((float4*)sWl)[q] = ((const float4*)Wl)[q];
    ((float4*)sWr)[q] = ((const float4*)Wr)[q];
  }
  __syncthreads();
  int lane = t & 63;
  int row = blockIdx.x * 4 + (t >> 6);
  if (row >= N_NODES) return;
  float xv = x[row * D + lane];
  float accl = bl[lane], accr = br[lane];
  #pragma unroll
  for (int k = 0; k < D; k++) {
    float xk = __shfl(xv, k, 64);
    accl = fmaf(xk, sWl[k * D + lane], accl);
    accr = fmaf(xk, sWr[k * D + lane], accr);
  }
  xlb[row * D + lane] = __float2bfloat16(accl);
  xr[row * D + lane] = accr;
}

// ---- histogram of dst (validated) ----
__global__ void k_hist(const int* __restrict__ ei, int* __restrict__ cursor) {
  int e = blockIdx.x * 256 + threadIdx.x;
  if (e < N_EDGES) atomicAdd(&cursor[ei[N_EDGES + e]], 1);
}

// ---- 3-kernel exclusive scan of counts -> row_start (validated) ----
__global__ void k_scan_a(const int* __restrict__ counts, int* __restrict__ row_start,
                         int* __restrict__ bsum) {
  __shared__ int sb[256];
  int t = threadIdx.x;
  int i = blockIdx.x * 256 + t;
  int v = (i < N_NODES) ? counts[i] : 0;
  sb[t] = v;
  __syncthreads();
  for (int off = 1; off < 256; off <<= 1) {
    int add = (t >= off) ? sb[t - off] : 0;
    __syncthreads();
    sb[t] += add;
    __syncthreads();
  }
  if (i < N_NODES) row_start[i] = sb[t] - v;  // exclusive
  if (t == 255) bsum[blockIdx.x] = sb[t];
}
__global__ void k_scan_b(int* __restrict__ bsum, int nb) {
  __shared__ int sb[256];
  int t = threadIdx.x;
  int v = (t < nb) ? bsum[t] : 0;
  sb[t] = v;
  __syncthreads();
  for (int off = 1; off < 256; off <<= 1) {
    int add = (t >= off) ? sb[t - off] : 0;
    __syncthreads();
    sb[t] += add;
    __syncthreads();
  }
  if (t < nb) bsum[t] = sb[t] - v;  // exclusive
}
__global__ void k_scan_c(int* __restrict__ row_start, const int* __restrict__ bsum,
                         int* __restrict__ cursor) {
  int t = threadIdx.x;
  int i = blockIdx.x * 256 + t;
  if (i < N_NODES) {
    int r = row_start[i] + bsum[blockIdx.x];
    row_start[i] = r;
    cursor[i] = r;
  }
  if (i == 0) row_start[N_NODES] = N_EDGES;
}

// ---- counting-sort scatter + edge-payload permute ----
// Writes src_perm[pos] (4 B) and the edge's 16 ea values as bf16 (32 B) into
// perm order, so k_fused reads edge data LINEARLY (no HBM gather in its loop).
__global__ void k_scatter(const int* __restrict__ ei, int* __restrict__ cursor,
                          int* __restrict__ src_perm, uint4* __restrict__ eap,
                          const float* __restrict__ ea) {
  int e = blockIdx.x * 256 + threadIdx.x;
  if (e >= N_EDGES) return;
  int s = ei[e];
  int d = ei[N_EDGES + e];
  // linear 64 B read of this edge's attributes
  const float4* ea4 = (const float4*)ea;
  float4 a = ea4[(size_t)e * 4 + 0];
  float4 b = ea4[(size_t)e * 4 + 1];
  float4 c = ea4[(size_t)e * 4 + 2];
  float4 f = ea4[(size_t)e * 4 + 3];
  int pos = atomicAdd(&cursor[d], 1);
  src_perm[pos] = s;
  uint4 w0, w1;
  w0.x = (unsigned)f2bf(a.x) | ((unsigned)f2bf(a.y) << 16);
  w0.y = (unsigned)f2bf(a.z) | ((unsigned)f2bf(a.w) << 16);
  w0.z = (unsigned)f2bf(b.x) | ((unsigned)f2bf(b.y) << 16);
  w0.w = (unsigned)f2bf(b.z) | ((unsigned)f2bf(b.w) << 16);
  w1.x = (unsigned)f2bf(c.x) | ((unsigned)f2bf(c.y) << 16);
  w1.y = (unsigned)f2bf(c.z) | ((unsigned)f2bf(c.w) << 16);
  w1.z = (unsigned)f2bf(f.x) | ((unsigned)f2bf(f.y) << 16);
  w1.w = (unsigned)f2bf(f.z) | ((unsigned)f2bf(f.w) << 16);
  eap[(size_t)pos * 2 + 0] = w0;
  eap[(size_t)pos * 2 + 1] = w1;
}

// ---- fused per-node online-softmax attention + aggregation (wave per node) ----
// Serial loop now has ONE random access (L2-resident xlb row); edge attrs are
// read linearly from ea_perm. 2-deep pipeline on the src->xlb chain.
__global__ __launch_bounds__(256) void k_fused(
    const unsigned short* __restrict__ eap, const float* __restrict__ We,
    const float* __restrict__ att,
    const __hip_bfloat16* __restrict__ xlb, const float* __restrict__ xr,
    const int* __restrict__ row_start, const int* __restrict__ src_perm,
    const float* __restrict__ bias, float* __restrict__ out) {
  __shared__ float sWe[ED * D];  // 4 KiB
  __shared__ float satt[D];
  int t = threadIdx.x;
  for (int q = t; q < ED * D / 4; q += 256) ((float4*)sWe)[q] = ((const float4*)We)[q];
  if (t < D) satt[t] = att[t];
  __syncthreads();
  int lane = t & 63;
  int n = blockIdx.x * 4 + (t >> 6);
  if (n >= N_NODES) return;
  int start = row_start[n];
  int end = row_start[n + 1];

  float xrv = xr[(size_t)n * D + lane];  // one linear row read per node
  float av = satt[lane];
  float m = -INFINITY, lsum = 0.f, O = 0.f;

  const unsigned short* xlr16 = (const unsigned short*)xlb;

  if (start < end) {
    int s0 = __builtin_amdgcn_readfirstlane(src_perm[start]);
    unsigned short xlr = xlr16[(size_t)s0 * D + lane];
    unsigned short ear = (lane < ED) ? eap[(size_t)start * ED + lane] : 0;
    int i1 = (start + 1 < end) ? start + 1 : start;
    int sp = src_perm[i1];

    for (int i = start; i < end; ++i) {
      // prefetch next edge: src->xlb gather + linear ea_perm row
      int s_n = __builtin_amdgcn_readfirstlane(sp);
      unsigned short xlr_n = xlr16[(size_t)s_n * D + lane];
      int inext = (i + 1 < end) ? i + 1 : i;
      unsigned short ear_n = (lane < ED) ? eap[(size_t)inext * ED + lane] : 0;
      int i2 = (i + 2 < end) ? i + 2 : i1;
      sp = src_perm[i2];

      // compute edge i
      float xlv = bf2f(xlr);
      float eavf = bf2f(ear);
      float acc = 0.f;
      #pragma unroll
      for (int k = 0; k < ED; k++) {
        float ek = __shfl(eavf, k, 64);
        acc = fmaf(ek, sWe[k * D + lane], acc);
      }
      float h = xlv + xrv + acc;
      h = (h > 0.f) ? h : NEG * h;
      float logit = wave_sum(h * av);
      // online softmax update
      float mn = fmaxf(m, logit);
      float sc = __expf(m - mn);
      float p = __expf(logit - mn);
      lsum = fmaf(lsum, sc, p);
      O = O * sc + p * xlv;
      m = mn;
      // rotate pipeline
      xlr = xlr_n;
      ear = ear_n;
    }
  }
  out[(size_t)n * D + lane] = O / (lsum + 1e-16f) + bias[lane];
}

static inline char* align_up(char* p, size_t a) {
  return (char*)(((uintptr_t)p + a - 1) & ~(uintptr_t)(a - 1));
}

extern "C" void kernel_launch(void* const* d_in, const int* in_sizes, int n_in,
                              void* d_out, int out_size, void* d_ws, size_t ws_size,
                              hipStream_t stream) {
  const float* x   = (const float*)d_in[0];
  const int* ei    = (const int*)d_in[1];   // harness passes integer inputs as int32 (validated)
  const float* ea  = (const float*)d_in[2];
  const float* Wl  = (const float*)d_in[3];
  const float* bl  = (const float*)d_in[4];
  const float* Wr  = (const float*)d_in[5];
  const float* br  = (const float*)d_in[6];
  const float* We  = (const float*)d_in[7];
  const float* att = (const float*)d_in[8];
  const float* bias = (const float*)d_in[9];
  float* out = (float*)d_out;

  // workspace carve-up (~56 MB), 256B-aligned blocks
  char* w = (char*)d_ws;
  __hip_bfloat16* xlb = (__hip_bfloat16*)w; w = align_up(w + (size_t)N_NODES * D * 2, 256);
  float* xr       = (float*)w; w = align_up(w + (size_t)N_NODES * D * 4, 256);
  int* row_start  = (int*)w;   w = align_up(w + (size_t)(N_NODES + 1) * 4, 256);
  int* cursor     = (int*)w;   w = align_up(w + (size_t)N_NODES * 4, 256);
  int* bsum       = (int*)w;   w = align_up(w + 256 * 4, 256);
  int* src_perm   = (int*)w;   w = align_up(w + (size_t)N_EDGES * 4, 256);
  uint4* eap      = (uint4*)w; w = align_up(w + (size_t)N_EDGES * ED * 2, 256);

  const int NB = (N_NODES + 255) / 256;  // 196

  hipMemsetAsync(cursor, 0, (size_t)N_NODES * 4, stream);
  k_transform<<<N_NODES / 4, 256, 0, stream>>>(x, Wl, bl, Wr, br, xlb, xr);
  k_hist<<<(N_EDGES + 255) / 256, 256, 0, stream>>>(ei, cursor);
  k_scan_a<<<NB, 256, 0, stream>>>(cursor, row_start, bsum);
  k_scan_b<<<1, 256, 0, stream>>>(bsum, NB);
  k_scan_c<<<NB, 256, 0, stream>>>(row_start, bsum, cursor);
  k_scatter<<<(N_EDGES + 255) / 256, 256, 0, stream>>>(ei, cursor, src_perm, eap, ea);
  k_fused<<<(N_NODES + 3) / 4, 256, 0, stream>>>((const unsigned short*)eap, We, att,
                                                 xlb, xr, row_start, src_perm, bias, out);
}